// Round 23
// baseline (66.539 us; speedup 1.0000x reference)
//
#include <hip/hip_runtime.h>

#define N_NODES 50000
#define N_EDGES 800000
#define D 64
#define NB 196            // buckets; bucket = id >> 8; 196*256 = 50176 >= 50000
#define BSZ 256           // nodes per bucket
#define NSLICE 256        // edge slices == CU count; 256*3136 = 802816 >= 800000
#define SLICE_E 3136      // edges per slice
#define SLICE_I4 784      // int4 groups per slice
#define E4 (N_EDGES / 4)  // 200000 int4 groups
#define ZROW N_NODES      // dummy zero row index (padded CSR entries)
#define BSTRIDE 8192      // per-bucket csr region; max padded total ~6600

typedef float floatx4 __attribute__((ext_vector_type(4)));  // native vec for NT builtins

// bf16 helpers (round-to-nearest-even); fp32 accumulation everywhere.
__device__ __forceinline__ ushort f2bf(float f) {
    unsigned u = __float_as_uint(f);
    unsigned r = u + 0x7fffu + ((u >> 16) & 1u);
    return (ushort)(r >> 16);
}
__device__ __forceinline__ void acc8(const uint4 a, float* acc) {
    acc[0] += __uint_as_float(a.x << 16);
    acc[1] += __uint_as_float(a.x & 0xffff0000u);
    acc[2] += __uint_as_float(a.y << 16);
    acc[3] += __uint_as_float(a.y & 0xffff0000u);
    acc[4] += __uint_as_float(a.z << 16);
    acc[5] += __uint_as_float(a.z & 0xffff0000u);
    acc[6] += __uint_as_float(a.w << 16);
    acc[7] += __uint_as_float(a.w & 0xffff0000u);
}

// ---------------------------------------------------------------------------
// K1: single-pass partition into COMPACT per-slice cells (r20: two
// concurrent single-wave shfl scans, no block-barrier storm).
// ---------------------------------------------------------------------------
__global__ __launch_bounds__(1024) void part1_kernel(
        const int* __restrict__ s, const int* __restrict__ r,
        unsigned* __restrict__ prc, unsigned char* __restrict__ psc,
        int* __restrict__ rcnt, int* __restrict__ scnt,
        int* __restrict__ roffg, int* __restrict__ soffg) {
    __shared__ unsigned lprc[SLICE_E];        // 12544 B compact receiver cells
    __shared__ unsigned char lpsc[SLICE_E];   //  3136 B compact sender cells
    __shared__ int rcur[NB], scur[NB];        // counts (preserved)
    __shared__ int rof[NB], sof[NB];          // offsets -> cursors
    const int tid = threadIdx.x, sl = blockIdx.x;
    for (int i = tid; i < NB; i += 1024) { rcur[i] = 0; scur[i] = 0; }
    __syncthreads();

    int e4 = sl * SLICE_I4 + tid;
    const bool act = (tid < SLICE_I4) && (e4 < E4);
    int4 rv, sv;
    if (act) {
        rv = ((const int4*)r)[e4];
        sv = ((const int4*)s)[e4];
        atomicAdd(&rcur[rv.x >> 8], 1); atomicAdd(&rcur[rv.y >> 8], 1);
        atomicAdd(&rcur[rv.z >> 8], 1); atomicAdd(&rcur[rv.w >> 8], 1);
        atomicAdd(&scur[sv.x >> 8], 1); atomicAdd(&scur[sv.y >> 8], 1);
        atomicAdd(&scur[sv.z >> 8], 1); atomicAdd(&scur[sv.w >> 8], 1);
    }
    __syncthreads();

    // two concurrent single-wave exclusive scans (no block barriers)
    {
        const int wv = tid >> 6, lane = tid & 63;
        if (wv < 2) {
            const int* cnt = wv ? scur : rcur;
            int* off = wv ? sof : rof;
            const int base = lane * 4;
            int c0 = (base + 0 < NB) ? cnt[base + 0] : 0;
            int c1 = (base + 1 < NB) ? cnt[base + 1] : 0;
            int c2 = (base + 2 < NB) ? cnt[base + 2] : 0;
            int c3 = (base + 3 < NB) ? cnt[base + 3] : 0;
            int sum = c0 + c1 + c2 + c3;
            int sv_ = sum;
            #pragma unroll
            for (int o = 1; o < 64; o <<= 1) {
                int u = __shfl_up(sv_, o);
                if (lane >= o) sv_ += u;
            }
            int excl = sv_ - sum;
            if (base + 0 < NB) off[base + 0] = excl;
            if (base + 1 < NB) off[base + 1] = excl + c0;
            if (base + 2 < NB) off[base + 2] = excl + c0 + c1;
            if (base + 3 < NB) off[base + 3] = excl + c0 + c1 + c2;
        }
    }
    __syncthreads();

    // persist counts + offsets before cursors are destroyed
    if (tid < NB) {
        rcnt[sl * NB + tid] = rcur[tid];
        scnt[sl * NB + tid] = scur[tid];
        roffg[sl * NB + tid] = rof[tid];
        soffg[sl * NB + tid] = sof[tid];
    }
    __syncthreads();

    // pass B: scatter into compact LDS via cursor atomics
    if (act) {
        int ri[4] = {rv.x, rv.y, rv.z, rv.w};
        int si[4] = {sv.x, sv.y, sv.z, sv.w};
        #pragma unroll
        for (int k = 0; k < 4; ++k) {
            int pos = atomicAdd(&rof[ri[k] >> 8], 1);
            lprc[pos] = ((unsigned)(ri[k] & 255) << 16) | (unsigned)si[k];
            int pos2 = atomicAdd(&sof[si[k] >> 8], 1);
            lpsc[pos2] = (unsigned char)(si[k] & 255);
        }
    }
    __syncthreads();

    // coalesced compact writeout
    if (tid < SLICE_I4)
        ((uint4*)(prc + (size_t)sl * SLICE_E))[tid] = ((const uint4*)lprc)[tid];
    if (tid < SLICE_E / 16)
        ((uint4*)(psc + (size_t)sl * SLICE_E))[tid] = ((const uint4*)lpsc)[tid];
}

// ---------------------------------------------------------------------------
// K2 (merged): blocks [0,NB) build PAD-TO-8 per-bucket CSR (fixed-stride
// bucket regions); pads point at zero row ZROW. Blocks [NB,2NB) compute
// sender scales + LDS-tiled linear (r17 structure).
// ---------------------------------------------------------------------------
__global__ __launch_bounds__(256, 4) void post_kernel(
        const unsigned* __restrict__ prc, const unsigned char* __restrict__ psc,
        const int* __restrict__ rcnt, const int* __restrict__ scnt,
        const int* __restrict__ roffg, const int* __restrict__ soffg,
        int* __restrict__ rowoff, int* __restrict__ rdeg,
        ushort* __restrict__ csr16,
        const float* __restrict__ x, const float* __restrict__ w,
        const float* __restrict__ bias, ushort* __restrict__ h16) {
    __shared__ int sc[256];
    __shared__ int h4[BSZ];
    __shared__ float wlds[64 * 68];   // W staged (padded rows)
    __shared__ float xlds[64 * 68];   // x tile
    __shared__ float slds[BSZ];       // per-node scale
    __shared__ float blds[64];        // bias
    const int tid = threadIdx.x;

    if (blockIdx.x >= NB) {
        // ---- sscale + linear for sender bucket b ----
        const int b = blockIdx.x - NB;
        h4[tid] = 0;
        if (tid < 64) blds[tid] = bias[tid];
        if (b == 0 && tid < 8)    // zero row for CSR pads
            ((uint4*)(h16 + (size_t)ZROW * D))[tid] = make_uint4(0u, 0u, 0u, 0u);
        __syncthreads();
        {
            int sl = tid;                       // exactly one slice per thread
            int c = scnt[sl * NB + b];
            const unsigned char* cell = psc + (size_t)sl * SLICE_E + soffg[sl * NB + b];
            for (int i = 0; i < c; ++i) atomicAdd(&h4[cell[i]], 1);
        }
        __syncthreads();
        slds[tid] = rsqrtf((float)(h4[tid] + 1));   // +1 self edge
        // stage W once: 1024 float4
        #pragma unroll
        for (int q = 0; q < 4; ++q) {
            int idx = q * 256 + tid;
            int o = idx >> 4, k4 = idx & 15;
            float4 wv = ((const float4*)w)[idx];
            *(float4*)&wlds[o * 68 + k4 * 4] = wv;
        }
        __syncthreads();

        const int t15 = tid & 15;
        const int g = tid >> 4;           // 0..15: node group (4 nodes each)
        for (int tile = 0; tile < 4; ++tile) {
            const int nb = b * BSZ + tile * 64;
            #pragma unroll
            for (int q = 0; q < 4; ++q) {
                int idx = q * 256 + tid;
                int nl = idx >> 4, k4 = idx & 15;
                int n = nb + nl;
                float4 xv = (n < N_NODES) ? ((const float4*)x)[n * 16 + k4]
                                          : make_float4(0.f, 0.f, 0.f, 0.f);
                *(float4*)&xlds[nl * 68 + k4 * 4] = xv;
            }
            __syncthreads();

            float acc[4][4];
            #pragma unroll
            for (int i = 0; i < 4; ++i)
                #pragma unroll
                for (int j = 0; j < 4; ++j) acc[i][j] = 0.f;

            #pragma unroll 2
            for (int k4 = 0; k4 < 16; ++k4) {
                float4 wv0 = *(const float4*)&wlds[(t15     ) * 68 + k4 * 4];
                float4 wv1 = *(const float4*)&wlds[(t15 + 16) * 68 + k4 * 4];
                float4 wv2 = *(const float4*)&wlds[(t15 + 32) * 68 + k4 * 4];
                float4 wv3 = *(const float4*)&wlds[(t15 + 48) * 68 + k4 * 4];
                #pragma unroll
                for (int i = 0; i < 4; ++i) {
                    float4 xv = *(const float4*)&xlds[(g * 4 + i) * 68 + k4 * 4];
                    acc[i][0] += xv.x * wv0.x + xv.y * wv0.y + xv.z * wv0.z + xv.w * wv0.w;
                    acc[i][1] += xv.x * wv1.x + xv.y * wv1.y + xv.z * wv1.z + xv.w * wv1.w;
                    acc[i][2] += xv.x * wv2.x + xv.y * wv2.y + xv.z * wv2.z + xv.w * wv2.w;
                    acc[i][3] += xv.x * wv3.x + xv.y * wv3.y + xv.z * wv3.z + xv.w * wv3.w;
                }
            }

            #pragma unroll
            for (int i = 0; i < 4; ++i) {
                int nl = g * 4 + i;
                int n = nb + nl;
                if (n < N_NODES) {
                    float scl = slds[tile * 64 + nl];
                    h16[n * D + t15     ] = f2bf((acc[i][0] + blds[t15     ]) * scl);
                    h16[n * D + t15 + 16] = f2bf((acc[i][1] + blds[t15 + 16]) * scl);
                    h16[n * D + t15 + 32] = f2bf((acc[i][2] + blds[t15 + 32]) * scl);
                    h16[n * D + t15 + 48] = f2bf((acc[i][3] + blds[t15 + 48]) * scl);
                }
            }
            __syncthreads();   // xlds reused next tile
        }
        return;
    }

    // ---- pad-to-8 CSR for receiver bucket b (fixed-stride region) ----
    const int b = blockIdx.x;

    // node-level hist (one slice-cell per thread)
    h4[tid] = 0;
    __syncthreads();
    {
        int sl = tid;
        int c = rcnt[sl * NB + b];
        const unsigned* cell = prc + (size_t)sl * SLICE_E + roffg[sl * NB + b];
        for (int i = 0; i < c; ++i) atomicAdd(&h4[cell[i] >> 16], 1);
    }
    __syncthreads();

    // padded-count scan -> rowoff (bucket-local, fixed stride) + cursors
    int c = h4[tid];
    int pc = (c + 7) & ~7;
    int n = b * BSZ + tid;
    if (n >= N_NODES) { c = 0; pc = 0; }
    sc[tid] = pc;
    __syncthreads();
    for (int o = 1; o < 256; o <<= 1) {
        int u = (tid >= o) ? sc[tid - o] : 0;
        __syncthreads();
        sc[tid] += u;
        __syncthreads();
    }
    int start = b * BSTRIDE + sc[tid] - pc;
    if (n < N_NODES) {
        rowoff[n] = start;
        rdeg[n] = (pc << 16) | c;
    }
    h4[tid] = start;                     // reuse h4 as cursor array
    // fill pad slots with the zero-row sender
    for (int i = start + c; i < start + pc; ++i) csr16[i] = (ushort)ZROW;
    __syncthreads();

    // scatter senders into per-node csr (one slice-cell per thread)
    {
        int sl = tid;
        int cc = rcnt[sl * NB + b];
        const unsigned* cell = prc + (size_t)sl * SLICE_E + roffg[sl * NB + b];
        for (int i = 0; i < cc; ++i) {
            unsigned pw = cell[i];
            int pos = atomicAdd(&h4[pw >> 16], 1);
            csr16[pos] = (ushort)(pw & 0xffffu);
        }
    }
}

// ---------------------------------------------------------------------------
// K3: gather-accumulate, uniform pad-to-8. NONTEMPORAL csr16 loads and out
// stores (keep h16 resident in L2 — out write-allocate was evicting it).
// ---------------------------------------------------------------------------
__global__ __launch_bounds__(256) void gather_kernel(
        const ushort* __restrict__ h16, const int* __restrict__ rowoff,
        const int* __restrict__ rdeg, const ushort* __restrict__ csr16,
        float* __restrict__ out) {
    const int lane = threadIdx.x & 63;
    const int q = lane & 7;        // channel octet: channels q*8 .. q*8+7
    const int g = lane >> 3;       // edge sub-slot 0..7
    const int n = blockIdx.x * 4 + (threadIdx.x >> 6);
    if (n >= N_NODES) return;

    float acc[8];
    #pragma unroll
    for (int k = 0; k < 8; ++k) acc[k] = 0.f;

    const int base = rowoff[n];
    const unsigned word = (unsigned)rdeg[n];
    const int cnt = (int)(word & 0xffffu);
    const int pcnt = (int)(word >> 16);

    for (int j0 = 0; j0 < pcnt; j0 += 64) {
        int m = pcnt - j0; if (m > 64) m = 64;   // multiple of 8
        int my = (lane < m)
            ? (int)__builtin_nontemporal_load(&csr16[base + j0 + lane]) : 0;
        int t = 0;
        for (; t + 16 <= m; t += 16) {           // two full 8-edge slots
            int s0 = __shfl(my, t + g);
            int s1 = __shfl(my, t + 8 + g);
            uint4 a = *(const uint4*)&h16[s0 * D + q * 8];
            uint4 b = *(const uint4*)&h16[s1 * D + q * 8];
            acc8(a, acc);
            acc8(b, acc);
        }
        if (t < m) {                             // one final 8-slot (uniform)
            int s0 = __shfl(my, t + g);
            uint4 a = *(const uint4*)&h16[s0 * D + q * 8];
            acc8(a, acc);
        }
    }

    // butterfly: afterwards every lane holds the full sums
    #pragma unroll
    for (int k = 0; k < 8; ++k) acc[k] += __shfl_xor(acc[k], 8);
    #pragma unroll
    for (int k = 0; k < 8; ++k) acc[k] += __shfl_xor(acc[k], 16);
    #pragma unroll
    for (int k = 0; k < 8; ++k) acc[k] += __shfl_xor(acc[k], 32);

    uint4 sv = *(const uint4*)&h16[n * D + q * 8];
    acc8(sv, acc);
    float sc = rsqrtf((float)(cnt + 1));
    float o[8];
    #pragma unroll
    for (int k = 0; k < 8; ++k) {
        float vv = acc[k] * sc;
        o[k] = vv > 0.f ? vv : 0.01f * vv;
    }
    if (g == 0) {
        floatx4 v = {o[0], o[1], o[2], o[3]};
        __builtin_nontemporal_store(v, (floatx4*)(out + n * D + q * 8));
    } else if (g == 1) {
        floatx4 v = {o[4], o[5], o[6], o[7]};
        __builtin_nontemporal_store(v, (floatx4*)(out + n * D + q * 8 + 4));
    }
}

// ---------------------------------------------------------------------------
extern "C" void kernel_launch(void* const* d_in, const int* in_sizes, int n_in,
                              void* d_out, int out_size, void* d_ws, size_t ws_size,
                              hipStream_t stream) {
    const float* x       = (const float*)d_in[0];
    const int*   senders = (const int*)d_in[1];
    const int*   recvs   = (const int*)d_in[2];
    const float* weight  = (const float*)d_in[3];
    const float* bias    = (const float*)d_in[4];
    float* out = (float*)d_out;

    // workspace layout (256B-aligned chunks), ~16 MB total
    char* p = (char*)d_ws;
    auto take = [&](size_t bytes) { char* q = p; p += (bytes + 255) & ~(size_t)255; return q; };
    ushort*        h16    = (ushort*)take((size_t)(N_NODES + 1) * D * 2);   // 6.4 MB (+zero row)
    unsigned*      prc    = (unsigned*)take((size_t)NSLICE * SLICE_E * 4);  // 3.2 MB
    unsigned char* psc    = (unsigned char*)take((size_t)NSLICE * SLICE_E); // 0.8 MB
    int*           rcnt   = (int*)take((size_t)NSLICE * NB * 4);            // 200 KB
    int*           scnt   = (int*)take((size_t)NSLICE * NB * 4);            // 200 KB
    int*           roffg  = (int*)take((size_t)NSLICE * NB * 4);            // 200 KB
    int*           soffg  = (int*)take((size_t)NSLICE * NB * 4);            // 200 KB
    int*           rowoff = (int*)take((size_t)N_NODES * 4);                // 200 KB
    int*           rdeg   = (int*)take((size_t)N_NODES * 4);                // 200 KB
    ushort*        csr16  = (ushort*)take((size_t)NB * BSTRIDE * 2);        // 3.2 MB

    hipLaunchKernelGGL(part1_kernel, dim3(NSLICE), dim3(1024), 0, stream,
                       senders, recvs, prc, psc, rcnt, scnt, roffg, soffg);
    hipLaunchKernelGGL(post_kernel, dim3(2 * NB), dim3(BSZ), 0, stream,
                       prc, psc, rcnt, scnt, roffg, soffg, rowoff, rdeg, csr16,
                       x, weight, bias, h16);
    hipLaunchKernelGGL(gather_kernel, dim3((N_NODES + 3) / 4), dim3(256), 0, stream,
                       h16, rowoff, rdeg, csr16, out);
}

// Round 24
// 62.657 us; speedup vs baseline: 1.0620x; 1.0620x over previous
//
#include <hip/hip_runtime.h>

#define N_NODES 50000
#define N_EDGES 800000
#define D 64
#define NB 196            // buckets; bucket = id >> 8; 196*256 = 50176 >= 50000
#define BSZ 256           // nodes per bucket
#define NSLICE 256        // edge slices == CU count; 256*3136 = 802816 >= 800000
#define SLICE_E 3136      // edges per slice
#define SLICE_I4 784      // int4 groups per slice
#define E4 (N_EDGES / 4)  // 200000 int4 groups
#define ZROW N_NODES      // dummy zero row index (padded CSR entries)
#define BSTRIDE 8192      // per-bucket csr region; max padded total ~6600

// bf16 helpers (round-to-nearest-even); fp32 accumulation everywhere.
__device__ __forceinline__ ushort f2bf(float f) {
    unsigned u = __float_as_uint(f);
    unsigned r = u + 0x7fffu + ((u >> 16) & 1u);
    return (ushort)(r >> 16);
}
__device__ __forceinline__ void acc8(const uint4 a, float* acc) {
    acc[0] += __uint_as_float(a.x << 16);
    acc[1] += __uint_as_float(a.x & 0xffff0000u);
    acc[2] += __uint_as_float(a.y << 16);
    acc[3] += __uint_as_float(a.y & 0xffff0000u);
    acc[4] += __uint_as_float(a.z << 16);
    acc[5] += __uint_as_float(a.z & 0xffff0000u);
    acc[6] += __uint_as_float(a.w << 16);
    acc[7] += __uint_as_float(a.w & 0xffff0000u);
}

// ---------------------------------------------------------------------------
// K1: single-pass partition into COMPACT per-slice cells (r20: two
// concurrent single-wave shfl scans, no block-barrier storm).
// ---------------------------------------------------------------------------
__global__ __launch_bounds__(1024) void part1_kernel(
        const int* __restrict__ s, const int* __restrict__ r,
        unsigned* __restrict__ prc, unsigned char* __restrict__ psc,
        int* __restrict__ rcnt, int* __restrict__ scnt,
        int* __restrict__ roffg, int* __restrict__ soffg) {
    __shared__ unsigned lprc[SLICE_E];        // 12544 B compact receiver cells
    __shared__ unsigned char lpsc[SLICE_E];   //  3136 B compact sender cells
    __shared__ int rcur[NB], scur[NB];        // counts (preserved)
    __shared__ int rof[NB], sof[NB];          // offsets -> cursors
    const int tid = threadIdx.x, sl = blockIdx.x;
    for (int i = tid; i < NB; i += 1024) { rcur[i] = 0; scur[i] = 0; }
    __syncthreads();

    int e4 = sl * SLICE_I4 + tid;
    const bool act = (tid < SLICE_I4) && (e4 < E4);
    int4 rv, sv;
    if (act) {
        rv = ((const int4*)r)[e4];
        sv = ((const int4*)s)[e4];
        atomicAdd(&rcur[rv.x >> 8], 1); atomicAdd(&rcur[rv.y >> 8], 1);
        atomicAdd(&rcur[rv.z >> 8], 1); atomicAdd(&rcur[rv.w >> 8], 1);
        atomicAdd(&scur[sv.x >> 8], 1); atomicAdd(&scur[sv.y >> 8], 1);
        atomicAdd(&scur[sv.z >> 8], 1); atomicAdd(&scur[sv.w >> 8], 1);
    }
    __syncthreads();

    // two concurrent single-wave exclusive scans (no block barriers)
    {
        const int wv = tid >> 6, lane = tid & 63;
        if (wv < 2) {
            const int* cnt = wv ? scur : rcur;
            int* off = wv ? sof : rof;
            const int base = lane * 4;
            int c0 = (base + 0 < NB) ? cnt[base + 0] : 0;
            int c1 = (base + 1 < NB) ? cnt[base + 1] : 0;
            int c2 = (base + 2 < NB) ? cnt[base + 2] : 0;
            int c3 = (base + 3 < NB) ? cnt[base + 3] : 0;
            int sum = c0 + c1 + c2 + c3;
            int sv_ = sum;
            #pragma unroll
            for (int o = 1; o < 64; o <<= 1) {
                int u = __shfl_up(sv_, o);
                if (lane >= o) sv_ += u;
            }
            int excl = sv_ - sum;
            if (base + 0 < NB) off[base + 0] = excl;
            if (base + 1 < NB) off[base + 1] = excl + c0;
            if (base + 2 < NB) off[base + 2] = excl + c0 + c1;
            if (base + 3 < NB) off[base + 3] = excl + c0 + c1 + c2;
        }
    }
    __syncthreads();

    // persist counts + offsets before cursors are destroyed
    if (tid < NB) {
        rcnt[sl * NB + tid] = rcur[tid];
        scnt[sl * NB + tid] = scur[tid];
        roffg[sl * NB + tid] = rof[tid];
        soffg[sl * NB + tid] = sof[tid];
    }
    __syncthreads();

    // pass B: scatter into compact LDS via cursor atomics
    if (act) {
        int ri[4] = {rv.x, rv.y, rv.z, rv.w};
        int si[4] = {sv.x, sv.y, sv.z, sv.w};
        #pragma unroll
        for (int k = 0; k < 4; ++k) {
            int pos = atomicAdd(&rof[ri[k] >> 8], 1);
            lprc[pos] = ((unsigned)(ri[k] & 255) << 16) | (unsigned)si[k];
            int pos2 = atomicAdd(&sof[si[k] >> 8], 1);
            lpsc[pos2] = (unsigned char)(si[k] & 255);
        }
    }
    __syncthreads();

    // coalesced compact writeout
    if (tid < SLICE_I4)
        ((uint4*)(prc + (size_t)sl * SLICE_E))[tid] = ((const uint4*)lprc)[tid];
    if (tid < SLICE_E / 16)
        ((uint4*)(psc + (size_t)sl * SLICE_E))[tid] = ((const uint4*)lpsc)[tid];
}

// ---------------------------------------------------------------------------
// K2 (merged): blocks [0,NB) build PAD-TO-8 per-bucket CSR (fixed-stride
// bucket regions); pads point at zero row ZROW. Blocks [NB,2NB) compute
// sender scales + LDS-tiled linear (r17 structure).
// ---------------------------------------------------------------------------
__global__ __launch_bounds__(256, 4) void post_kernel(
        const unsigned* __restrict__ prc, const unsigned char* __restrict__ psc,
        const int* __restrict__ rcnt, const int* __restrict__ scnt,
        const int* __restrict__ roffg, const int* __restrict__ soffg,
        int* __restrict__ rowdeg, ushort* __restrict__ csr16,
        const float* __restrict__ x, const float* __restrict__ w,
        const float* __restrict__ bias, ushort* __restrict__ h16) {
    __shared__ int sc[256];
    __shared__ int h4[BSZ];
    __shared__ float wlds[64 * 68];   // W staged (padded rows)
    __shared__ float xlds[64 * 68];   // x tile
    __shared__ float slds[BSZ];       // per-node scale
    __shared__ float blds[64];        // bias
    const int tid = threadIdx.x;

    if (blockIdx.x >= NB) {
        // ---- sscale + linear for sender bucket b ----
        const int b = blockIdx.x - NB;
        h4[tid] = 0;
        if (tid < 64) blds[tid] = bias[tid];
        if (b == 0 && tid < 8)    // zero row for CSR pads
            ((uint4*)(h16 + (size_t)ZROW * D))[tid] = make_uint4(0u, 0u, 0u, 0u);
        __syncthreads();
        {
            int sl = tid;                       // exactly one slice per thread
            int c = scnt[sl * NB + b];
            const unsigned char* cell = psc + (size_t)sl * SLICE_E + soffg[sl * NB + b];
            for (int i = 0; i < c; ++i) atomicAdd(&h4[cell[i]], 1);
        }
        __syncthreads();
        slds[tid] = rsqrtf((float)(h4[tid] + 1));   // +1 self edge
        // stage W once: 1024 float4
        #pragma unroll
        for (int q = 0; q < 4; ++q) {
            int idx = q * 256 + tid;
            int o = idx >> 4, k4 = idx & 15;
            float4 wv = ((const float4*)w)[idx];
            *(float4*)&wlds[o * 68 + k4 * 4] = wv;
        }
        __syncthreads();

        const int t15 = tid & 15;
        const int g = tid >> 4;           // 0..15: node group (4 nodes each)
        for (int tile = 0; tile < 4; ++tile) {
            const int nb = b * BSZ + tile * 64;
            #pragma unroll
            for (int q = 0; q < 4; ++q) {
                int idx = q * 256 + tid;
                int nl = idx >> 4, k4 = idx & 15;
                int n = nb + nl;
                float4 xv = (n < N_NODES) ? ((const float4*)x)[n * 16 + k4]
                                          : make_float4(0.f, 0.f, 0.f, 0.f);
                *(float4*)&xlds[nl * 68 + k4 * 4] = xv;
            }
            __syncthreads();

            float acc[4][4];
            #pragma unroll
            for (int i = 0; i < 4; ++i)
                #pragma unroll
                for (int j = 0; j < 4; ++j) acc[i][j] = 0.f;

            #pragma unroll 2
            for (int k4 = 0; k4 < 16; ++k4) {
                float4 wv0 = *(const float4*)&wlds[(t15     ) * 68 + k4 * 4];
                float4 wv1 = *(const float4*)&wlds[(t15 + 16) * 68 + k4 * 4];
                float4 wv2 = *(const float4*)&wlds[(t15 + 32) * 68 + k4 * 4];
                float4 wv3 = *(const float4*)&wlds[(t15 + 48) * 68 + k4 * 4];
                #pragma unroll
                for (int i = 0; i < 4; ++i) {
                    float4 xv = *(const float4*)&xlds[(g * 4 + i) * 68 + k4 * 4];
                    acc[i][0] += xv.x * wv0.x + xv.y * wv0.y + xv.z * wv0.z + xv.w * wv0.w;
                    acc[i][1] += xv.x * wv1.x + xv.y * wv1.y + xv.z * wv1.z + xv.w * wv1.w;
                    acc[i][2] += xv.x * wv2.x + xv.y * wv2.y + xv.z * wv2.z + xv.w * wv2.w;
                    acc[i][3] += xv.x * wv3.x + xv.y * wv3.y + xv.z * wv3.z + xv.w * wv3.w;
                }
            }

            #pragma unroll
            for (int i = 0; i < 4; ++i) {
                int nl = g * 4 + i;
                int n = nb + nl;
                if (n < N_NODES) {
                    float scl = slds[tile * 64 + nl];
                    h16[n * D + t15     ] = f2bf((acc[i][0] + blds[t15     ]) * scl);
                    h16[n * D + t15 + 16] = f2bf((acc[i][1] + blds[t15 + 16]) * scl);
                    h16[n * D + t15 + 32] = f2bf((acc[i][2] + blds[t15 + 32]) * scl);
                    h16[n * D + t15 + 48] = f2bf((acc[i][3] + blds[t15 + 48]) * scl);
                }
            }
            __syncthreads();   // xlds reused next tile
        }
        return;
    }

    // ---- pad-to-8 CSR for receiver bucket b (fixed-stride region) ----
    const int b = blockIdx.x;

    // node-level hist (one slice-cell per thread)
    h4[tid] = 0;
    __syncthreads();
    {
        int sl = tid;
        int c = rcnt[sl * NB + b];
        const unsigned* cell = prc + (size_t)sl * SLICE_E + roffg[sl * NB + b];
        for (int i = 0; i < c; ++i) atomicAdd(&h4[cell[i] >> 16], 1);
    }
    __syncthreads();

    // padded-count scan -> rowoff (bucket-local, fixed stride) + cursors
    int c = h4[tid];
    int pc = (c + 7) & ~7;
    int n = b * BSZ + tid;
    if (n >= N_NODES) { c = 0; pc = 0; }
    sc[tid] = pc;
    __syncthreads();
    for (int o = 1; o < 256; o <<= 1) {
        int u = (tid >= o) ? sc[tid - o] : 0;
        __syncthreads();
        sc[tid] += u;
        __syncthreads();
    }
    int start = b * BSTRIDE + sc[tid] - pc;
    if (n < N_NODES) {
        // packed [rowoff, (pc<<16)|c] for one int2 load in gather
        ((int2*)rowdeg)[n] = make_int2(start, (pc << 16) | c);
    }
    h4[tid] = start;                     // reuse h4 as cursor array
    // fill pad slots with the zero-row sender
    for (int i = start + c; i < start + pc; ++i) csr16[i] = (ushort)ZROW;
    __syncthreads();

    // scatter senders into per-node csr (one slice-cell per thread)
    {
        int sl = tid;
        int cc = rcnt[sl * NB + b];
        const unsigned* cell = prc + (size_t)sl * SLICE_E + roffg[sl * NB + b];
        for (int i = 0; i < cc; ++i) {
            unsigned pw = cell[i];
            int pos = atomicAdd(&h4[pw >> 16], 1);
            csr16[pos] = (ushort)(pw & 0xffffu);
        }
    }
}

// ---------------------------------------------------------------------------
// K3: gather-accumulate, uniform pad-to-8 (r21 best config; NT reverted —
// r23 showed NT stores regress). Wave per node; 8-lane group per row,
// uint4 (8 bf16) per lane; packed rowoff/rdeg int2 load.
// ---------------------------------------------------------------------------
__global__ __launch_bounds__(256) void gather_kernel(
        const ushort* __restrict__ h16, const int* __restrict__ rowdeg,
        const ushort* __restrict__ csr16, float* __restrict__ out) {
    const int lane = threadIdx.x & 63;
    const int q = lane & 7;        // channel octet: channels q*8 .. q*8+7
    const int g = lane >> 3;       // edge sub-slot 0..7
    const int n = blockIdx.x * 4 + (threadIdx.x >> 6);
    if (n >= N_NODES) return;

    float acc[8];
    #pragma unroll
    for (int k = 0; k < 8; ++k) acc[k] = 0.f;

    const int2 rd = ((const int2*)rowdeg)[n];
    const int base = rd.x;
    const int cnt = rd.y & 0xffff;
    const int pcnt = ((unsigned)rd.y) >> 16;

    for (int j0 = 0; j0 < pcnt; j0 += 64) {
        int m = pcnt - j0; if (m > 64) m = 64;   // multiple of 8
        int my = (lane < m) ? (int)csr16[base + j0 + lane] : 0;
        int t = 0;
        for (; t + 16 <= m; t += 16) {           // two full 8-edge slots
            int s0 = __shfl(my, t + g);
            int s1 = __shfl(my, t + 8 + g);
            uint4 a = *(const uint4*)&h16[s0 * D + q * 8];
            uint4 b = *(const uint4*)&h16[s1 * D + q * 8];
            acc8(a, acc);
            acc8(b, acc);
        }
        if (t < m) {                             // one final 8-slot (uniform)
            int s0 = __shfl(my, t + g);
            uint4 a = *(const uint4*)&h16[s0 * D + q * 8];
            acc8(a, acc);
        }
    }

    // butterfly: afterwards every lane holds the full sums
    #pragma unroll
    for (int k = 0; k < 8; ++k) acc[k] += __shfl_xor(acc[k], 8);
    #pragma unroll
    for (int k = 0; k < 8; ++k) acc[k] += __shfl_xor(acc[k], 16);
    #pragma unroll
    for (int k = 0; k < 8; ++k) acc[k] += __shfl_xor(acc[k], 32);

    uint4 sv = *(const uint4*)&h16[n * D + q * 8];
    acc8(sv, acc);
    float sc = rsqrtf((float)(cnt + 1));
    float o[8];
    #pragma unroll
    for (int k = 0; k < 8; ++k) {
        float vv = acc[k] * sc;
        o[k] = vv > 0.f ? vv : 0.01f * vv;
    }
    if (g == 0) {
        *(float4*)(out + n * D + q * 8)     = make_float4(o[0], o[1], o[2], o[3]);
    } else if (g == 1) {
        *(float4*)(out + n * D + q * 8 + 4) = make_float4(o[4], o[5], o[6], o[7]);
    }
}

// ---------------------------------------------------------------------------
extern "C" void kernel_launch(void* const* d_in, const int* in_sizes, int n_in,
                              void* d_out, int out_size, void* d_ws, size_t ws_size,
                              hipStream_t stream) {
    const float* x       = (const float*)d_in[0];
    const int*   senders = (const int*)d_in[1];
    const int*   recvs   = (const int*)d_in[2];
    const float* weight  = (const float*)d_in[3];
    const float* bias    = (const float*)d_in[4];
    float* out = (float*)d_out;

    // workspace layout (256B-aligned chunks), ~16 MB total
    char* p = (char*)d_ws;
    auto take = [&](size_t bytes) { char* q = p; p += (bytes + 255) & ~(size_t)255; return q; };
    ushort*        h16    = (ushort*)take((size_t)(N_NODES + 1) * D * 2);   // 6.4 MB (+zero row)
    unsigned*      prc    = (unsigned*)take((size_t)NSLICE * SLICE_E * 4);  // 3.2 MB
    unsigned char* psc    = (unsigned char*)take((size_t)NSLICE * SLICE_E); // 0.8 MB
    int*           rcnt   = (int*)take((size_t)NSLICE * NB * 4);            // 200 KB
    int*           scnt   = (int*)take((size_t)NSLICE * NB * 4);            // 200 KB
    int*           roffg  = (int*)take((size_t)NSLICE * NB * 4);            // 200 KB
    int*           soffg  = (int*)take((size_t)NSLICE * NB * 4);            // 200 KB
    int*           rowdeg = (int*)take((size_t)N_NODES * 8);                // 400 KB (int2/node)
    ushort*        csr16  = (ushort*)take((size_t)NB * BSTRIDE * 2);        // 3.2 MB

    hipLaunchKernelGGL(part1_kernel, dim3(NSLICE), dim3(1024), 0, stream,
                       senders, recvs, prc, psc, rcnt, scnt, roffg, soffg);
    hipLaunchKernelGGL(post_kernel, dim3(2 * NB), dim3(BSZ), 0, stream,
                       prc, psc, rcnt, scnt, roffg, soffg, rowdeg, csr16,
                       x, weight, bias, h16);
    hipLaunchKernelGGL(gather_kernel, dim3((N_NODES + 3) / 4), dim3(256), 0, stream,
                       h16, rowdeg, csr16, out);
}